// Round 1
// baseline (10921.549 us; speedup 1.0000x reference)
//
#include <hip/hip_runtime.h>
#include <hip/hip_fp16.h>
#include <hip/hip_cooperative_groups.h>

namespace cg = cooperative_groups;

// Problem dims (fixed by reference)
#define NB 512   // batch
#define NTT 256  // timesteps
#define ND 512   // input dim
#define NH 1024  // hidden dim
#define NK 1536  // ND + NH (fused K)

typedef _Float16 f16;
typedef f16 f16x8 __attribute__((ext_vector_type(8)));
typedef f16 f16x4 __attribute__((ext_vector_type(4)));
typedef float f32x4 __attribute__((ext_vector_type(4)));

// ws layout:
//   [0, WUT_BYTES)                : WUT f16 [NH][NK]  (WUT[n][k] = k<ND ? W[k][n] : U[k-ND][n])
//   [WUT_BYTES, +2*HBUF_BYTES)    : hbuf f16 [2][NB][NH]  ping-pong
#define WUT_BYTES (NH * NK * 2)      // 3,145,728
#define HBUF_BYTES (NB * NH * 2)     // 1,048,576

// ---------------------------------------------------------------------------
// Prep: build WUT = [W;U]^T in fp16 via LDS-tiled transpose.
// grid = 24 (k-tiles) x 16 (n-tiles) = 384 blocks, 256 threads.
// ---------------------------------------------------------------------------
__global__ void prep_wut(const float* __restrict__ W, const float* __restrict__ U,
                         f16* __restrict__ WUT) {
    __shared__ float tile[64][65];   // +1 pad: conflict-free transpose
    int bk = blockIdx.x % 24;        // k tile (0..23)
    int bn = blockIdx.x / 24;        // n tile (0..15)
    int k0 = bk * 64, n0 = bn * 64;
    int tid = threadIdx.x;
    int jn = tid & 63;
#pragma unroll
    for (int p = 0; p < 16; ++p) {
        int kr = p * 4 + (tid >> 6);
        int k = k0 + kr;
        float v = (k < ND) ? W[k * NH + n0 + jn] : U[(k - ND) * NH + n0 + jn];
        tile[kr][jn] = v;            // coalesced read of W/U rows
    }
    __syncthreads();
#pragma unroll
    for (int p = 0; p < 16; ++p) {
        int nr = p * 4 + (tid >> 6);
        int kc = tid & 63;
        WUT[(size_t)(n0 + nr) * NK + k0 + kc] = (f16)tile[kc][nr];  // coalesced write
    }
}

__device__ __forceinline__ float fast_tanh(float x) {
    // 2/(1+e^{-2x}) - 1 ; saturates correctly to +-1 for large |x| (inf-safe)
    float e = __expf(-2.0f * x);
    return 2.0f / (1.0f + e) - 1.0f;
}

// ---------------------------------------------------------------------------
// Persistent cooperative recurrence kernel.
// grid = 128 blocks (mt = bid>>4 in 0..7 -> 64 batch rows; nt = bid&15 -> 64 cols),
// 256 threads = 4 waves in 2x2, each wave a 32x32 tile via 16x16x32 fp16 MFMA.
// Per step: C = [x_t | h_t] @ WUT^T, h_new = tanh(C + b); grid sync; repeat.
// ---------------------------------------------------------------------------
__global__ void __launch_bounds__(256, 1)
rnn_persist(const float* __restrict__ x, const f16* __restrict__ WUT,
            f16* __restrict__ hbuf, const float* __restrict__ bias,
            const float* __restrict__ Wd, const float* __restrict__ bd,
            float* __restrict__ out) {
    // Row stride 72 f16 = 144 B = 9*16B: keeps every 8-elem chunk 16B-aligned
    // and rotates banks by 4 dwords/row (~2-way aliasing on b128 reads = free).
    __shared__ f16 As[64][72];
    __shared__ f16 Bs[64][72];
    __shared__ float bcol[64];

    cg::grid_group grid = cg::this_grid();

    const int bid = blockIdx.x;
    const int nt = bid & 15, mt = bid >> 4;
    const int r0 = mt * 64, c0 = nt * 64;
    const int tid = threadIdx.x;
    const int lane = tid & 63, wid = tid >> 6;
    const int wr0 = (wid >> 1) * 32, wc0 = (wid & 1) * 32;
    const int lrow = lane & 15, lq = lane >> 4;

    if (tid < 64) bcol[tid] = bias[c0 + tid];
    // (first use of bcol is after many __syncthreads in the K-loop)

    for (int t = 0; t < NTT; ++t) {
        const f16* hprev = hbuf + (size_t)(t & 1) * (NB * NH);
        f16* hnew = hbuf + (size_t)((t + 1) & 1) * (NB * NH);

        f32x4 acc00 = {0.f, 0.f, 0.f, 0.f};
        f32x4 acc01 = {0.f, 0.f, 0.f, 0.f};
        f32x4 acc10 = {0.f, 0.f, 0.f, 0.f};
        f32x4 acc11 = {0.f, 0.f, 0.f, 0.f};

        for (int kb = 0; kb < 24; ++kb) {
            const int k0 = kb * 64;
            if (kb < 8) {
                // A-tile from x (f32 -> f16 inline): 64 rows x 64 k
#pragma unroll
                for (int i = 0; i < 4; ++i) {
                    int idx = i * 256 + tid;
                    int row = idx >> 4;
                    int kl = (idx & 15) * 4;
                    const float4 v = *(const float4*)(x + ((size_t)(r0 + row) * NTT + t) * ND + k0 + kl);
                    f16x4 hv = {(f16)v.x, (f16)v.y, (f16)v.z, (f16)v.w};
                    *(f16x4*)(&As[row][kl]) = hv;
                }
            } else {
                // A-tile from h_prev (already f16): raw 16B copies
#pragma unroll
                for (int i = 0; i < 2; ++i) {
                    int idx = i * 256 + tid;
                    int row = idx >> 3;
                    int kl = (idx & 7) * 8;
                    *(uint4*)(&As[row][kl]) =
                        *(const uint4*)(hprev + (size_t)(r0 + row) * NH + (k0 - ND) + kl);
                }
            }
            // B-tile from WUT (Bs[n][k], i.e. B^T rows): raw 16B copies
#pragma unroll
            for (int i = 0; i < 2; ++i) {
                int idx = i * 256 + tid;
                int row = idx >> 3;
                int kl = (idx & 7) * 8;
                *(uint4*)(&Bs[row][kl]) =
                    *(const uint4*)(WUT + (size_t)(c0 + row) * NK + k0 + kl);
            }
            __syncthreads();
#pragma unroll
            for (int ks = 0; ks < 2; ++ks) {
                const int kk = ks * 32 + lq * 8;
                f16x8 a0 = *(const f16x8*)(&As[wr0 + lrow][kk]);
                f16x8 a1 = *(const f16x8*)(&As[wr0 + 16 + lrow][kk]);
                f16x8 b0 = *(const f16x8*)(&Bs[wc0 + lrow][kk]);
                f16x8 b1 = *(const f16x8*)(&Bs[wc0 + 16 + lrow][kk]);
                acc00 = __builtin_amdgcn_mfma_f32_16x16x32_f16(a0, b0, acc00, 0, 0, 0);
                acc01 = __builtin_amdgcn_mfma_f32_16x16x32_f16(a0, b1, acc01, 0, 0, 0);
                acc10 = __builtin_amdgcn_mfma_f32_16x16x32_f16(a1, b0, acc10, 0, 0, 0);
                acc11 = __builtin_amdgcn_mfma_f32_16x16x32_f16(a1, b1, acc11, 0, 0, 0);
            }
            __syncthreads();
        }

        // Epilogue: h_new = tanh(acc + b). C/D layout: col=lane&15, row=lq*4+reg.
#pragma unroll
        for (int i = 0; i < 2; ++i) {
            int rowb = r0 + wr0 + i * 16 + lq * 4;
#pragma unroll
            for (int j = 0; j < 2; ++j) {
                int colb = wc0 + j * 16 + lrow;
                float bb = bcol[colb];
                f32x4 a = (i == 0) ? ((j == 0) ? acc00 : acc01)
                                   : ((j == 0) ? acc10 : acc11);
#pragma unroll
                for (int r = 0; r < 4; ++r) {
                    float v = a[r] + bb;
                    hnew[(size_t)(rowb + r) * NH + (c0 + colb)] = (f16)fast_tanh(v);
                }
            }
        }
        grid.sync();   // h_t+1 fully visible before anyone reads it
    }

    // Final dense head: logits[b] = h_last . Wd + bd ; h_last = hbuf parity 0.
    if (bid < 8) {
        const f16* hlast = hbuf;           // (NTT is even)
        int r = tid >> 2;                  // 0..63
        int q = tid & 3;                   // 0..3 -> quarter of the H dim
        int row = bid * 64 + r;
        const f16* hp = hlast + (size_t)row * NH + q * 256;
        const float* wp = Wd + q * 256;
        float sum = 0.f;
#pragma unroll 4
        for (int i = 0; i < 256; i += 8) {
            f16x8 hv = *(const f16x8*)(hp + i);
            float4 w0 = *(const float4*)(wp + i);
            float4 w1 = *(const float4*)(wp + i + 4);
            sum += (float)hv[0] * w0.x + (float)hv[1] * w0.y +
                   (float)hv[2] * w0.z + (float)hv[3] * w0.w +
                   (float)hv[4] * w1.x + (float)hv[5] * w1.y +
                   (float)hv[6] * w1.z + (float)hv[7] * w1.w;
        }
        sum += __shfl_xor(sum, 1);
        sum += __shfl_xor(sum, 2);
        if (q == 0) out[row] = sum + bd[0];
    }
}

// ---------------------------------------------------------------------------
extern "C" void kernel_launch(void* const* d_in, const int* in_sizes, int n_in,
                              void* d_out, int out_size, void* d_ws, size_t ws_size,
                              hipStream_t stream) {
    const float* x  = (const float*)d_in[0];
    const float* W  = (const float*)d_in[1];
    const float* U  = (const float*)d_in[2];
    const float* b  = (const float*)d_in[3];
    const float* Wd = (const float*)d_in[4];
    const float* bd = (const float*)d_in[5];
    float* out = (float*)d_out;

    f16* WUT  = (f16*)d_ws;
    f16* hbuf = (f16*)((char*)d_ws + WUT_BYTES);

    // h_0 = 0 (parity-0 buffer only; parity-1 is fully written at t=0)
    hipMemsetAsync(hbuf, 0, HBUF_BYTES, stream);
    prep_wut<<<dim3(384), dim3(256), 0, stream>>>(W, U, WUT);

    void* args[7] = {(void*)&x, (void*)&WUT, (void*)&hbuf, (void*)&b,
                     (void*)&Wd, (void*)&bd, (void*)&out};
    hipLaunchCooperativeKernel(reinterpret_cast<const void*>(&rnn_persist),
                               dim3(128), dim3(256), args, 0, stream);
}

// Round 3
// 6215.619 us; speedup vs baseline: 1.7571x; 1.7571x over previous
//
#include <hip/hip_runtime.h>
#include <hip/hip_fp16.h>

// Problem dims (fixed by reference)
#define NB 512   // batch
#define NTT 256  // timesteps
#define ND 512   // input dim
#define NH 1024  // hidden dim

typedef _Float16 f16;
typedef f16 f16x8 __attribute__((ext_vector_type(8)));
typedef f16 f16x4 __attribute__((ext_vector_type(4)));
typedef float f32x4 __attribute__((ext_vector_type(4)));

// ws layout
#define BAR_BYTES 4096
#define UT_OFF  BAR_BYTES
#define UT_BYTES (NH * NH * 2)           // 2 MB  UT[n][k] = U[k][n]
#define WT_OFF  (UT_OFF + UT_BYTES)
#define WT_BYTES (NH * ND * 2)           // 1 MB  WT[h][d] = W[d][h]
#define H_OFF   (WT_OFF + WT_BYTES)
#define H_BYTES (2 * NB * NH * 2)        // 2 MB  ping-pong h
#define XW_OFF  (H_OFF + H_BYTES)        // + TC MB for xw chunk

// ---------------------------------------------------------------------------
// Transpose prep: D[n][k] = (f16)S[k][n].  S is [R][1024] f32.
// ---------------------------------------------------------------------------
__global__ void prep_tr(const float* __restrict__ S, f16* __restrict__ D, int R) {
    __shared__ float tile[64][65];
    int rt = R >> 6;
    int bk = blockIdx.x % rt, bn = blockIdx.x / rt;
    int k0 = bk * 64, n0 = bn * 64;
    int tid = threadIdx.x, jn = tid & 63;
#pragma unroll
    for (int p = 0; p < 16; ++p) {
        int kr = p * 4 + (tid >> 6);
        tile[kr][jn] = S[(size_t)(k0 + kr) * NH + n0 + jn];
    }
    __syncthreads();
#pragma unroll
    for (int p = 0; p < 16; ++p) {
        int nr = p * 4 + (tid >> 6);
        int kc = tid & 63;
        D[(size_t)(n0 + nr) * R + k0 + kc] = (f16)tile[kc][nr];
    }
}

__device__ __forceinline__ float fast_tanh(float x) {
    float e = __expf(-2.0f * x);
    return 2.0f / (1.0f + e) - 1.0f;
}

// Two-level grid barrier: 16 groups of 16 blocks -> root. Monotonic counters.
__device__ __forceinline__ void gbar(unsigned* bar, int ep, int bid, int tid) {
    __syncthreads();   // drain this block's global stores (vmcnt) before release
    if (tid == 0) {
        unsigned* gc = bar + (bid >> 4) * 32;      // 128 B apart
        unsigned* root = bar + 768;
        unsigned prev = __hip_atomic_fetch_add(gc, 1u, __ATOMIC_RELEASE, __HIP_MEMORY_SCOPE_AGENT);
        if (prev == (unsigned)(ep * 16 - 1))
            __hip_atomic_fetch_add(root, 1u, __ATOMIC_RELEASE, __HIP_MEMORY_SCOPE_AGENT);
        while (__hip_atomic_load(root, __ATOMIC_ACQUIRE, __HIP_MEMORY_SCOPE_AGENT)
               < (unsigned)(ep * 16)) {
            __builtin_amdgcn_s_sleep(2);
        }
    }
    __syncthreads();
}

union SharedU {
    struct { f16 As[128][72]; f16 Bs[128][72]; } a;  // Phase A: 36864 B
    struct { float red[4 * 2176]; } r;                // reduction: 34816 B
};
static_assert(sizeof(SharedU) <= 64 * 1024, "LDS over 64 KiB");

// ---------------------------------------------------------------------------
// Persistent kernel. 256 blocks x 256 threads (4 waves), 1 block/CU.
// Per chunk of TC steps:
//   Phase A: xw[tc][b][h] = x_t @ W + b   (128x128 tiles, BK=64 streamed)
//   Steps:   h_new = tanh(h_prev @ U + xw_t)
//     - 32x64 block tile (mt=bid>>4 rows, nt=bid&15 cols), 4 waves split K (256 each)
//     - B (UT cols) resident in 128 VGPRs/lane for the whole chunk
//     - A-frags loaded directly from global h_prev (L2-resident)
//     - 4-partial split-K reduction via LDS
// ---------------------------------------------------------------------------
__global__ void __launch_bounds__(256, 1)
rnn3(const float* __restrict__ x, const f16* __restrict__ UT,
     const f16* __restrict__ WT, const float* __restrict__ bias,
     const float* __restrict__ Wd, const float* __restrict__ bd,
     f16* __restrict__ xw, f16* __restrict__ h, unsigned* __restrict__ bar,
     float* __restrict__ out, int TC) {
    __shared__ SharedU sh;
    const int bid = blockIdx.x, tid = threadIdx.x;
    const int lane = tid & 63, wid = tid >> 6;
    const int lrow = lane & 15, lq = lane >> 4;
    const int nt = bid & 15, mt = bid >> 4;
    const int r0 = mt * 32, c0 = nt * 64;
    int ep = 0;

    const int nchunks = NTT / TC;
    for (int ch = 0; ch < nchunks; ++ch) {
        // ---------------- Phase A: xw = x_t @ W + b ----------------
        const int units = TC * 32;   // (TC*4 row-tiles of 128) x (8 col-tiles of 128)
        for (int u = bid; u < units; u += 256) {
            const int ct = u & 7, rt = u >> 3;
            const int tcl = rt >> 2, b0 = (rt & 3) * 128;
            const int tg = ch * TC + tcl;
            const int c0A = ct * 128;
            const int wr = (wid >> 1) * 64, wc = (wid & 1) * 64;
            f32x4 acc[4][4] = {};
            for (int kc = 0; kc < 8; ++kc) {
                __syncthreads();   // guard prior LDS reads (also vs reduction use)
#pragma unroll
                for (int p = 0; p < 8; ++p) {   // As: 128 rows x 64 k (f32 -> f16)
                    int idx = p * 256 + tid;
                    int row = idx >> 4, c4 = idx & 15;
                    const float4 v = *(const float4*)(x + ((size_t)(b0 + row) * NTT + tg) * ND
                                                      + kc * 64 + c4 * 4);
                    f16x4 hv = {(f16)v.x, (f16)v.y, (f16)v.z, (f16)v.w};
                    *(f16x4*)(&sh.a.As[row][c4 * 4]) = hv;
                }
#pragma unroll
                for (int p = 0; p < 4; ++p) {   // Bs: 128 rows x 64 k
                    int idx = p * 256 + tid;
                    int row = idx >> 3, c8 = idx & 7;
                    *(uint4*)(&sh.a.Bs[row][c8 * 8]) =
                        *(const uint4*)(WT + (size_t)(c0A + row) * ND + kc * 64 + c8 * 8);
                }
                __syncthreads();
#pragma unroll
                for (int ks = 0; ks < 2; ++ks) {
                    const int kk = ks * 32 + lq * 8;
                    f16x8 af[4], bf[4];
#pragma unroll
                    for (int i = 0; i < 4; ++i)
                        af[i] = *(const f16x8*)(&sh.a.As[wr + i * 16 + lrow][kk]);
#pragma unroll
                    for (int j = 0; j < 4; ++j)
                        bf[j] = *(const f16x8*)(&sh.a.Bs[wc + j * 16 + lrow][kk]);
#pragma unroll
                    for (int i = 0; i < 4; ++i)
#pragma unroll
                        for (int j = 0; j < 4; ++j)
                            acc[i][j] = __builtin_amdgcn_mfma_f32_16x16x32_f16(af[i], bf[j], acc[i][j], 0, 0, 0);
                }
            }
            // epilogue: xw = acc + bias
#pragma unroll
            for (int j = 0; j < 4; ++j) {
                const int colg = c0A + wc + j * 16 + lrow;
                const float bb = bias[colg];
#pragma unroll
                for (int i = 0; i < 4; ++i) {
                    const int rl = wr + i * 16 + lq * 4;
#pragma unroll
                    for (int rg = 0; rg < 4; ++rg)
                        xw[((size_t)tcl * NB + b0 + rl + rg) * NH + colg] =
                            (f16)(acc[i][j][rg] + bb);
                }
            }
        }
        gbar(bar, ++ep, bid, tid);

        // B resident: UT rows c0..c0+63, K-quarter wid*256. 128 VGPRs/lane.
        f16x8 breg[4][8];
#pragma unroll
        for (int j = 0; j < 4; ++j)
#pragma unroll
            for (int it = 0; it < 8; ++it)
                breg[j][it] = *(const f16x8*)(UT + (size_t)(c0 + j * 16 + lrow) * NH
                                              + wid * 256 + it * 32 + lq * 8);

        // ---------------- recurrence ----------------
        for (int tc = 0; tc < TC; ++tc) {
            const int t = ch * TC + tc;
            const f16* hprev = h + (size_t)(t & 1) * (NB * NH);
            f16* hnew = h + (size_t)((t + 1) & 1) * (NB * NH);
            f32x4 acc[2][4] = {};
            const f16* aP = hprev + (size_t)(r0 + lrow) * NH + wid * 256 + lq * 8;
#pragma unroll
            for (int it = 0; it < 8; ++it) {
                f16x8 a0 = *(const f16x8*)(aP + it * 32);
                f16x8 a1 = *(const f16x8*)(aP + (size_t)16 * NH + it * 32);
#pragma unroll
                for (int j = 0; j < 4; ++j) {
                    acc[0][j] = __builtin_amdgcn_mfma_f32_16x16x32_f16(a0, breg[j][it], acc[0][j], 0, 0, 0);
                    acc[1][j] = __builtin_amdgcn_mfma_f32_16x16x32_f16(a1, breg[j][it], acc[1][j], 0, 0, 0);
                }
            }
            // 4-way split-K reduction via LDS
            float* myr = sh.r.red + wid * 2176;
#pragma unroll
            for (int g = 0; g < 8; ++g)
                *(f32x4*)(myr + g * 272 + lq * 68 + lrow * 4) = acc[g >> 2][g & 3];
            __syncthreads();
#pragma unroll
            for (int gg = 0; gg < 2; ++gg) {
                const int g = wid * 2 + gg, i = g >> 2, j = g & 3;
                const int off = g * 272 + lq * 68 + lrow * 4;
                f32x4 s = *(const f32x4*)(sh.r.red + off);
#pragma unroll
                for (int w = 1; w < 4; ++w)
                    s += *(const f32x4*)(sh.r.red + w * 2176 + off);
                const int rowb = r0 + i * 16 + lq * 4;
                const int colg = c0 + j * 16 + lrow;
                const f16* xwp = xw + ((size_t)tc * NB + rowb) * NH + colg;
                f16* hp = hnew + (size_t)rowb * NH + colg;
#pragma unroll
                for (int rg = 0; rg < 4; ++rg) {
                    float v = s[rg] + (float)xwp[(size_t)rg * NH];
                    hp[(size_t)rg * NH] = (f16)fast_tanh(v);
                }
            }
            gbar(bar, ++ep, bid, tid);
        }
    }

    // Dense head on h_last (parity 0 since NTT even)
    if (bid < 8) {
        const f16* hlast = h;
        int r = tid >> 2, q = tid & 3;
        int row = bid * 64 + r;
        const f16* hp = hlast + (size_t)row * NH + q * 256;
        const float* wp = Wd + q * 256;
        float sum = 0.f;
#pragma unroll 4
        for (int i = 0; i < 256; i += 8) {
            f16x8 hv = *(const f16x8*)(hp + i);
            float4 w0 = *(const float4*)(wp + i);
            float4 w1 = *(const float4*)(wp + i + 4);
            sum += (float)hv[0] * w0.x + (float)hv[1] * w0.y +
                   (float)hv[2] * w0.z + (float)hv[3] * w0.w +
                   (float)hv[4] * w1.x + (float)hv[5] * w1.y +
                   (float)hv[6] * w1.z + (float)hv[7] * w1.w;
        }
        sum += __shfl_xor(sum, 1);
        sum += __shfl_xor(sum, 2);
        if (q == 0) out[row] = sum + bd[0];
    }
}

// ---------------------------------------------------------------------------
extern "C" void kernel_launch(void* const* d_in, const int* in_sizes, int n_in,
                              void* d_out, int out_size, void* d_ws, size_t ws_size,
                              hipStream_t stream) {
    const float* x  = (const float*)d_in[0];
    const float* W  = (const float*)d_in[1];
    const float* U  = (const float*)d_in[2];
    const float* b  = (const float*)d_in[3];
    const float* Wd = (const float*)d_in[4];
    const float* bd = (const float*)d_in[5];
    float* out = (float*)d_out;

    char* ws = (char*)d_ws;
    unsigned* bar = (unsigned*)ws;
    f16* UT = (f16*)(ws + UT_OFF);
    f16* WT = (f16*)(ws + WT_OFF);
    f16* h  = (f16*)(ws + H_OFF);
    f16* xw = (f16*)(ws + XW_OFF);

    // Largest power-of-2 chunk of timesteps whose xw buffer fits in ws.
    int TC = 32;
    while (TC > 1 && (size_t)XW_OFF + (size_t)TC * NB * NH * 2 > ws_size) TC >>= 1;

    hipMemsetAsync(bar, 0, BAR_BYTES, stream);
    hipMemsetAsync(h, 0, NB * NH * 2, stream);
    prep_tr<<<dim3(256), dim3(256), 0, stream>>>(U, UT, NH);
    prep_tr<<<dim3(128), dim3(256), 0, stream>>>(W, WT, ND);

    void* args[11] = {(void*)&x, (void*)&UT, (void*)&WT, (void*)&b, (void*)&Wd,
                      (void*)&bd, (void*)&xw, (void*)&h, (void*)&bar, (void*)&out,
                      (void*)&TC};
    hipError_t err = hipLaunchCooperativeKernel(
        reinterpret_cast<const void*>(&rnn3), dim3(256), dim3(256), args, 0, stream);
    if (err != hipSuccess) {
        // Fallback: plain launch. 256 blocks <= 256 CUs at this footprint are
        // co-resident; the kernel uses its own global barrier (gbar), not cg.
        rnn3<<<dim3(256), dim3(256), 0, stream>>>(x, UT, WT, b, Wd, bd, xw, h,
                                                  bar, out, TC);
    }
}

// Round 4
// 5305.294 us; speedup vs baseline: 2.0586x; 1.1716x over previous
//
#include <hip/hip_runtime.h>
#include <hip/hip_fp16.h>

// Problem dims (fixed by reference)
#define NB 512   // batch
#define NTT 256  // timesteps
#define ND 512   // input dim
#define NH 1024  // hidden dim
#define NK 1536  // ND + NH fused K

typedef _Float16 f16;
typedef f16 f16x8 __attribute__((ext_vector_type(8)));
typedef f16 f16x4 __attribute__((ext_vector_type(4)));
typedef float f32x4 __attribute__((ext_vector_type(4)));

union U16x8 { unsigned long long q[2]; f16x8 v; uint4 u4; };

// ws layout
#define BAR_BYTES 4096
#define WUT_OFF  BAR_BYTES
#define WUT_BYTES (NH * NK * 2)          // 3 MB: WUT[n][k] = k<512 ? W[k][n] : U[k-512][n]
#define H_OFF    (WUT_OFF + WUT_BYTES)
#define H_BYTES  (2 * NB * NH * 2)       // 2 MB ping-pong h

// ---------------------------------------------------------------------------
// Prep: WUT = [W;U]^T in fp16. grid = 24 (k-tiles) x 16 (n-tiles) = 384 blocks.
// ---------------------------------------------------------------------------
__global__ void prep_wut(const float* __restrict__ W, const float* __restrict__ U,
                         f16* __restrict__ WUT) {
    __shared__ float tile[64][65];
    int bk = blockIdx.x % 24, bn = blockIdx.x / 24;
    int k0 = bk * 64, n0 = bn * 64;
    int tid = threadIdx.x, jn = tid & 63;
#pragma unroll
    for (int p = 0; p < 16; ++p) {
        int kr = p * 4 + (tid >> 6);
        int k = k0 + kr;
        float v = (k < ND) ? W[(size_t)k * NH + n0 + jn] : U[(size_t)(k - ND) * NH + n0 + jn];
        tile[kr][jn] = v;
    }
    __syncthreads();
#pragma unroll
    for (int p = 0; p < 16; ++p) {
        int nr = p * 4 + (tid >> 6);
        int kc = tid & 63;
        WUT[(size_t)(n0 + nr) * NK + k0 + kc] = (f16)tile[kc][nr];
    }
}

__device__ __forceinline__ float fast_tanh(float x) {
    float e = __expf(-2.0f * x);
    return 2.0f / (1.0f + e) - 1.0f;
}

// ---------------------------------------------------------------------------
// Persistent kernel: 256 blocks x 512 threads (8 waves).
// 16 independent clusters of 16 blocks (co-XCD heuristic via bid&7; correctness
// does not depend on placement — cross-block traffic is agent-scope atomics).
// Cluster owns 32 batch rows; block owns 64 cols, weights register-resident
// (fused K=1536: x-part prefetched from global, h-part exchanged per step).
// 8 waves split K 8-ways: wave w: x-k [w*64,+64), h-k [w*128,+128).
// ---------------------------------------------------------------------------
__global__ void __launch_bounds__(512, 1)
rnn4(const float* __restrict__ x, const f16* __restrict__ WUT,
     const float* __restrict__ bias, const float* __restrict__ Wd,
     const float* __restrict__ bd, f16* __restrict__ h,
     unsigned* __restrict__ bar, float* __restrict__ out) {
    __shared__ float red[4][64][36];   // [buf][col][row+pad] f32, 36864 B
    __shared__ f16 trans[32][72];      // epilogue transpose, 4608 B

    const int bid = blockIdx.x, tid = threadIdx.x;
    const int lane = tid & 63, wid = tid >> 6;
    const int lrow = lane & 15, lq = lane >> 4;
    const int xcd = bid & 7, m8 = bid >> 3;
    const int cl = xcd * 2 + (m8 >> 4);     // 0..15
    const int mem = m8 & 15;                // 0..15
    const int r0 = cl * 32, c0 = mem * 64;
    const int kx0 = wid * 64;               // x k-slice base
    const int kh0 = wid * 128;              // h k-slice base (global k = 512+kh0)
    unsigned* cnt = bar + cl * 32;          // 128-B spaced cluster counters

    // ---- weights: register-resident WUT slice [c0..c0+64) x wave k-slice ----
    f16x8 bw[4][6];   // [j][kt]: kt 0..1 x-part, 2..5 h-part. 96 VGPRs.
    float bias_r[4];
#pragma unroll
    for (int j = 0; j < 4; ++j) {
        const int col = c0 + j * 16 + lrow;
        bias_r[j] = bias[col];
        const f16* wp = WUT + (size_t)col * NK;
#pragma unroll
        for (int kt = 0; kt < 2; ++kt)
            bw[j][kt] = *(const f16x8*)(wp + kx0 + kt * 32 + lq * 8);
#pragma unroll
        for (int kt = 0; kt < 4; ++kt)
            bw[j][2 + kt] = *(const f16x8*)(wp + ND + kh0 + kt * 32 + lq * 8);
    }

    // ---- x prefetch for t=0 ----
    float4 xf[2][2][2];   // [m][kt][half]
    {
        const int t0 = 0;
#pragma unroll
        for (int m = 0; m < 2; ++m) {
            const float* xp = x + (size_t)(r0 + m * 16 + lrow) * (NTT * ND)
                                + (size_t)t0 * ND + kx0 + lq * 8;
#pragma unroll
            for (int kt = 0; kt < 2; ++kt) {
                xf[m][kt][0] = *(const float4*)(xp + kt * 32);
                xf[m][kt][1] = *(const float4*)(xp + kt * 32 + 4);
            }
        }
    }

    for (int t = 0; t < NTT; ++t) {
        const f16* hprev = h + (size_t)(t & 1) * (NB * NH);
        f16* hnew = h + (size_t)((t + 1) & 1) * (NB * NH);

        // convert prefetched x to fragments
        f16x8 ax[2][2];
#pragma unroll
        for (int m = 0; m < 2; ++m)
#pragma unroll
            for (int kt = 0; kt < 2; ++kt) {
                const float4 a = xf[m][kt][0], b = xf[m][kt][1];
                f16x8 v = {(f16)a.x, (f16)a.y, (f16)a.z, (f16)a.w,
                           (f16)b.x, (f16)b.y, (f16)b.z, (f16)b.w};
                ax[m][kt] = v;
            }

        f32x4 acc[2][4] = {};
        // x-part MFMAs
#pragma unroll
        for (int kt = 0; kt < 2; ++kt)
#pragma unroll
            for (int m = 0; m < 2; ++m)
#pragma unroll
                for (int j = 0; j < 4; ++j)
                    acc[m][j] = __builtin_amdgcn_mfma_f32_16x16x32_f16(ax[m][kt], bw[j][kt], acc[m][j], 0, 0, 0);

        // h-part: agent-scope atomic loads (cross-XCD safe), then MFMA
#pragma unroll
        for (int kt = 0; kt < 4; ++kt) {
            U16x8 a0, a1;
            const f16* p0 = hprev + (size_t)(r0 + lrow) * NH + kh0 + kt * 32 + lq * 8;
            const f16* p1 = p0 + (size_t)16 * NH;
            a0.q[0] = __hip_atomic_load((const unsigned long long*)p0, __ATOMIC_RELAXED, __HIP_MEMORY_SCOPE_AGENT);
            a0.q[1] = __hip_atomic_load((const unsigned long long*)p0 + 1, __ATOMIC_RELAXED, __HIP_MEMORY_SCOPE_AGENT);
            a1.q[0] = __hip_atomic_load((const unsigned long long*)p1, __ATOMIC_RELAXED, __HIP_MEMORY_SCOPE_AGENT);
            a1.q[1] = __hip_atomic_load((const unsigned long long*)p1 + 1, __ATOMIC_RELAXED, __HIP_MEMORY_SCOPE_AGENT);
#pragma unroll
            for (int j = 0; j < 4; ++j) {
                acc[0][j] = __builtin_amdgcn_mfma_f32_16x16x32_f16(a0.v, bw[j][2 + kt], acc[0][j], 0, 0, 0);
                acc[1][j] = __builtin_amdgcn_mfma_f32_16x16x32_f16(a1.v, bw[j][2 + kt], acc[1][j], 0, 0, 0);
            }
        }

        // ---- 8 -> 1 split-K tree reduction in LDS ----
#define ST_PARTIAL(B)                                                          \
        {                                                                      \
            _Pragma("unroll")                                                  \
            for (int m = 0; m < 2; ++m)                                        \
                _Pragma("unroll")                                              \
                for (int j = 0; j < 4; ++j)                                    \
                    *(f32x4*)&red[B][j * 16 + lrow][m * 16 + lq * 4] = acc[m][j]; \
        }
#define ADD_PARTIAL(B)                                                         \
        {                                                                      \
            _Pragma("unroll")                                                  \
            for (int m = 0; m < 2; ++m)                                        \
                _Pragma("unroll")                                              \
                for (int j = 0; j < 4; ++j)                                    \
                    acc[m][j] += *(const f32x4*)&red[B][j * 16 + lrow][m * 16 + lq * 4]; \
        }
        if (wid >= 4) ST_PARTIAL(wid - 4);
        __syncthreads();
        if (wid < 4) ADD_PARTIAL(wid);
        __syncthreads();
        if (wid == 2 || wid == 3) ST_PARTIAL(wid - 2);
        __syncthreads();
        if (wid < 2) ADD_PARTIAL(wid);
        __syncthreads();
        if (wid == 1) ST_PARTIAL(0);
        __syncthreads();

        // ---- epilogue (wave 0): bias + tanh, transpose, store h_new ----
        if (wid == 0) {
            ADD_PARTIAL(0);
#pragma unroll
            for (int m = 0; m < 2; ++m)
#pragma unroll
                for (int j = 0; j < 4; ++j) {
                    const int c = j * 16 + lrow, rb = m * 16 + lq * 4;
#pragma unroll
                    for (int r = 0; r < 4; ++r)
                        trans[rb + r][c] = (f16)fast_tanh(acc[m][j][r] + bias_r[j]);
                }
            // wave-local LDS write->read (compiler inserts lgkmcnt)
            const int rr = lane >> 1, ch = (lane & 1) * 32;
            f16* dst = hnew + (size_t)(r0 + rr) * NH + c0 + ch;
#pragma unroll
            for (int s = 0; s < 4; ++s) {
                U16x8 u; u.v = *(const f16x8*)&trans[rr][ch + s * 8];
                __hip_atomic_store((unsigned long long*)(dst + s * 8), u.q[0], __ATOMIC_RELAXED, __HIP_MEMORY_SCOPE_AGENT);
                __hip_atomic_store((unsigned long long*)(dst + s * 8) + 1, u.q[1], __ATOMIC_RELAXED, __HIP_MEMORY_SCOPE_AGENT);
            }
        }

        // ---- prefetch x for t+1 (latency hides under barrier) ----
        const int tn = (t + 1 < NTT) ? t + 1 : NTT - 1;
#pragma unroll
        for (int m = 0; m < 2; ++m) {
            const float* xp = x + (size_t)(r0 + m * 16 + lrow) * (NTT * ND)
                                + (size_t)tn * ND + kx0 + lq * 8;
#pragma unroll
            for (int kt = 0; kt < 2; ++kt) {
                xf[m][kt][0] = *(const float4*)(xp + kt * 32);
                xf[m][kt][1] = *(const float4*)(xp + kt * 32 + 4);
            }
        }

        // ---- cluster barrier (16 blocks, relaxed atomics + safety fences) ----
        __syncthreads();   // drains each wave's stores (vmcnt) before release
        if (tid == 0) {
            __threadfence();   // belt-and-suspenders release (wbl2)
            __hip_atomic_fetch_add(cnt, 1u, __ATOMIC_RELAXED, __HIP_MEMORY_SCOPE_AGENT);
            const unsigned want = 16u * (unsigned)(t + 1);
            while (__hip_atomic_load(cnt, __ATOMIC_RELAXED, __HIP_MEMORY_SCOPE_AGENT) < want)
                __builtin_amdgcn_s_sleep(1);
            __threadfence();   // acquire (inv)
        }
        __syncthreads();
    }

    // ---- dense head: cluster leader computes out[r0..r0+32) ----
    if (mem == 0) {
        const f16* hlast = h;                   // parity 0 (NTT even)
        const int r = tid >> 4, seg = tid & 15; // 32 rows x 16 segments of 64
        const f16* hp = hlast + (size_t)(r0 + r) * NH + seg * 64;
        const float* wp = Wd + seg * 64;
        float s = 0.f;
#pragma unroll
        for (int i = 0; i < 64; i += 8) {
            U16x8 u;
            u.q[0] = __hip_atomic_load((const unsigned long long*)(hp + i), __ATOMIC_RELAXED, __HIP_MEMORY_SCOPE_AGENT);
            u.q[1] = __hip_atomic_load((const unsigned long long*)(hp + i) + 1, __ATOMIC_RELAXED, __HIP_MEMORY_SCOPE_AGENT);
            const float4 w0 = *(const float4*)(wp + i);
            const float4 w1 = *(const float4*)(wp + i + 4);
            s += (float)u.v[0] * w0.x + (float)u.v[1] * w0.y +
                 (float)u.v[2] * w0.z + (float)u.v[3] * w0.w +
                 (float)u.v[4] * w1.x + (float)u.v[5] * w1.y +
                 (float)u.v[6] * w1.z + (float)u.v[7] * w1.w;
        }
        s += __shfl_xor(s, 1); s += __shfl_xor(s, 2);
        s += __shfl_xor(s, 4); s += __shfl_xor(s, 8);
        if (seg == 0) out[r0 + r] = s + bd[0];
    }
}

// ---------------------------------------------------------------------------
extern "C" void kernel_launch(void* const* d_in, const int* in_sizes, int n_in,
                              void* d_out, int out_size, void* d_ws, size_t ws_size,
                              hipStream_t stream) {
    const float* x  = (const float*)d_in[0];
    const float* W  = (const float*)d_in[1];
    const float* U  = (const float*)d_in[2];
    const float* b  = (const float*)d_in[3];
    const float* Wd = (const float*)d_in[4];
    const float* bd = (const float*)d_in[5];
    float* out = (float*)d_out;

    char* ws = (char*)d_ws;
    unsigned* bar = (unsigned*)ws;
    f16* WUT = (f16*)(ws + WUT_OFF);
    f16* h   = (f16*)(ws + H_OFF);

    hipMemsetAsync(bar, 0, BAR_BYTES, stream);
    hipMemsetAsync(h, 0, NB * NH * 2, stream);   // h_0 = 0 (parity 0)
    prep_wut<<<dim3(384), dim3(256), 0, stream>>>(W, U, WUT);

    void* args[8] = {(void*)&x, (void*)&WUT, (void*)&b, (void*)&Wd,
                     (void*)&bd, (void*)&h, (void*)&bar, (void*)&out};
    hipError_t err = hipLaunchCooperativeKernel(
        reinterpret_cast<const void*>(&rnn4), dim3(256), dim3(512), args, 0, stream);
    if (err != hipSuccess) {
        // Plain-launch fallback: 256 blocks of 8 waves fit 1/CU on 256 CUs;
        // sync is our own cluster-local atomic barrier, not cg.
        rnn4<<<dim3(256), dim3(512), 0, stream>>>(x, WUT, b, Wd, bd, h, bar, out);
    }
}